// Round 7
// baseline (619.500 us; speedup 1.0000x reference)
//
#include <hip/hip_runtime.h>
#include <stdint.h>

#define BATCH 128
#define SEQ   256
#define NC    16
#define HID   256
#define G4    1024

typedef _Float16 half8 __attribute__((ext_vector_type(8)));
typedef float    f32x4 __attribute__((ext_vector_type(4)));

__device__ __forceinline__ uint16_t f32_to_f16u(float f){
  union { _Float16 h; uint16_t u; } c; c.h = (_Float16)f; return c.u;
}
__device__ __forceinline__ float f16u_to_f32(uint32_t u){
  union { uint16_t u; _Float16 h; } c; c.u = (uint16_t)u; return (float)c.h;
}
__device__ __forceinline__ float tanh_(float x){
  x = fminf(fmaxf(x, -15.f), 15.f);
  float e = __expf(2.f * x);
  return (e - 1.f) / (e + 1.f);
}
__device__ __forceinline__ float sigm_(float x){ return 1.f / (1.f + __expf(-x)); }

__device__ __forceinline__ int sdot4_(uint32_t a, int b, int c){
#if __has_builtin(__builtin_amdgcn_sdot4)
  return __builtin_amdgcn_sdot4((int)a, b, c, false);
#else
  int ai = (int)a, bi = b;
  c += ((ai << 24) >> 24) * ((bi << 24) >> 24);
  c += ((ai << 16) >> 24) * ((bi << 16) >> 24);
  c += ((ai <<  8) >> 24) * ((bi <<  8) >> 24);
  c += ( ai >> 24)        * ( bi >> 24);
  return c;
#endif
}
__device__ __forceinline__ uint32_t q4(const float* s, float sc){
  uint32_t r = 0;
  #pragma unroll
  for (int i = 0; i < 4; i++){
    int q = __float2int_rn(s[i] * sc);
    q = max(-127, min(127, q));
    r |= ((uint32_t)(q & 0xFF)) << (8 * i);
  }
  return r;
}

// ---- Wall pack for R7 recurrence ----
// read: ww[rr][jw] = wpk[(jw*2+rr)*512 + t]; t=(u<<1)|gp; row = u + (gp*2+rr)*256; k = jw*4..+3
__global__ void pack_wall_r7(const float* __restrict__ W, uint32_t* __restrict__ out){
  int L = blockIdx.x * blockDim.x + threadIdx.x;
  if (L >= 64 * 1024) return;
  int t = L & 511, rr = (L >> 9) & 1, jw = L >> 10;
  int u = t >> 1, gp = t & 1;
  int row = u + (gp * 2 + rr) * 256;
  out[L] = q4(W + (size_t)row * 256 + jw * 4, 2032.f);
}
// ---- Wd pack: wd[jw] = wdp[jw*512 + t]; row = u (full row, pair-redundant)
__global__ void pack_wd_r7(const float* __restrict__ W, uint32_t* __restrict__ out){
  int L = blockIdx.x * blockDim.x + threadIdx.x;
  if (L >= 32 * 1024) return;
  int t = L & 511, jw = L >> 9;
  int u = t >> 1;
  out[L] = q4(W + (size_t)u * 256 + jw * 4, 2032.f);
}

__global__ void pack_u16(const float* __restrict__ W, uint16_t* __restrict__ out, int n){
  int i = blockIdx.x * blockDim.x + threadIdx.x;
  if (i < n) out[i] = f32_to_f16u(W[i]);
}

__global__ void ts_k(const float* __restrict__ times, float* __restrict__ ts_all){
  int i = blockIdx.x * blockDim.x + threadIdx.x;
  if (i < BATCH * SEQ) ts_all[i] = 1.f / logf(times[i] + 2.7183f);
}

__global__ void gather_x(const int* __restrict__ codes, const float* __restrict__ mask,
                         const float* __restrict__ emb, uint16_t* __restrict__ xh){
  int bs = blockIdx.x;
  int t  = threadIdx.x;
  __shared__ int   scd[NC];
  __shared__ float smk[NC];
  if (t < NC){ scd[t] = codes[bs * NC + t]; smk[t] = mask[bs * NC + t]; }
  __syncthreads();
  float acc = 0.f;
  #pragma unroll
  for (int k = 0; k < NC; k++)
    acc += emb[(size_t)scd[k] * HID + t] * smk[k];
  xh[(size_t)bs * HID + t] = f32_to_f16u(acc);
}

// ---- xp GEMM via MFMA f16 (unchanged): xp2[m][u*4+gate] f16
__global__ __launch_bounds__(256, 2) void xp_gemm_mfma(
    const uint16_t* __restrict__ xh, const uint16_t* __restrict__ uh,
    const float* __restrict__ Ub, uint16_t* __restrict__ xp2)
{
  __shared__ _Float16 As[128][40];
  __shared__ _Float16 Bs[128][40];
  const int tid = threadIdx.x;
  const int m0 = blockIdx.y * 128, n0 = blockIdx.x * 128;
  const int w = tid >> 6, l = tid & 63;
  const int wr = w >> 1, wc = w & 1;
  const int sr0 = tid >> 2, sk0 = (tid & 3) * 8;

  f32x4 acc[4][4];
  #pragma unroll
  for (int i = 0; i < 4; i++)
    #pragma unroll
    for (int j = 0; j < 4; j++)
      acc[i][j] = (f32x4){0.f, 0.f, 0.f, 0.f};

  for (int k0 = 0; k0 < 256; k0 += 32){
    uint4 a0 = *(const uint4*)(xh + (size_t)(m0 + sr0) * 256 + k0 + sk0);
    uint4 a1 = *(const uint4*)(xh + (size_t)(m0 + 64 + sr0) * 256 + k0 + sk0);
    uint4 b0 = *(const uint4*)(uh + (size_t)(n0 + sr0) * 256 + k0 + sk0);
    uint4 b1 = *(const uint4*)(uh + (size_t)(n0 + 64 + sr0) * 256 + k0 + sk0);
    __syncthreads();
    *(uint4*)&As[sr0][sk0]      = a0;
    *(uint4*)&As[64 + sr0][sk0] = a1;
    *(uint4*)&Bs[sr0][sk0]      = b0;
    *(uint4*)&Bs[64 + sr0][sk0] = b1;
    __syncthreads();
    half8 af[4], bf[4];
    #pragma unroll
    for (int i = 0; i < 4; i++)
      af[i] = *(half8*)&As[wr*64 + i*16 + (l & 15)][(l >> 4) * 8];
    #pragma unroll
    for (int j = 0; j < 4; j++)
      bf[j] = *(half8*)&Bs[wc*64 + j*16 + (l & 15)][(l >> 4) * 8];
    #pragma unroll
    for (int i = 0; i < 4; i++)
      #pragma unroll
      for (int j = 0; j < 4; j++)
        acc[i][j] = __builtin_amdgcn_mfma_f32_16x16x32_f16(af[i], bf[j], acc[i][j], 0, 0, 0);
  }

  const int gate = n0 >> 8;
  #pragma unroll
  for (int j = 0; j < 4; j++){
    int ncol = wc*64 + j*16 + (l & 15);
    float bs = Ub[n0 + ncol];
    int u = (n0 & 255) + ncol;
    #pragma unroll
    for (int i = 0; i < 4; i++){
      #pragma unroll
      for (int r = 0; r < 4; r++){
        int m_e = m0 + wr*64 + i*16 + (l >> 4)*4 + r;
        xp2[(size_t)m_e * 1024 + u*4 + gate] = f32_to_f16u(acc[i][j][r] + bs);
      }
    }
  }
}

// ---- recurrence R7: 128 blocks x 512 threads (8 waves, 2/SIMD)
// thread (u=t>>1, gp=t&1): Wall rows u+(gp*2+rr)*256 (rr=0,1) full K + full Wd row u.
// h/c broadcast via one coalesced ds_read_b64 per wave + v_readlane -> SGPR -> sdot4.
__global__ __launch_bounds__(512, 2) void recurrence(
    const uint32_t* __restrict__ wpk,   // [64][2][512]
    const uint32_t* __restrict__ wdp,   // [64][512]
    const float* __restrict__ Wall_b, const float* __restrict__ Wd_b,
    const uint16_t* __restrict__ xp2, const float* __restrict__ ts_all,
    float* __restrict__ out)
{
  const int b = blockIdx.x, t = threadIdx.x;
  const int u = t >> 1, gp = t & 1, lane = t & 63;
  const bool odd = (gp != 0);

  __shared__ __align__(16) uint2 hc[2][64];   // word j: {h units 4j..4j+3 i8, c units 4j..4j+3 i8}

  uint32_t ww0[64], ww1[64], wd[64];
  #pragma unroll
  for (int jw = 0; jw < 64; jw++){
    ww0[jw] = wpk[(jw * 2 + 0) * 512 + t];
    ww1[jw] = wpk[(jw * 2 + 1) * 512 + t];
    wd[jw]  = wdp[jw * 512 + t];
  }

  const float b0 = Wall_b[u + gp * 512];         // gp0: f ; gp1: o
  const float b1 = Wall_b[u + gp * 512 + 256];   // gp0: i ; gp1: c
  const float bD = Wd_b[u];
  const float SW  = 1.f / (2032.f * 127.f);
  const float SWD = 1.f / (2032.f * 15.875f);

  if (t < 64) hc[0][t] = make_uint2(0u, 0u);
  __syncthreads();

  const uint16_t* xp_b = xp2 + (size_t)b * SEQ * 1024;
  const float*    ts_b = ts_all + (size_t)b * SEQ;
  float* out_b = out + (size_t)b * SEQ * HID;

  float c_reg = 0.f, hn_prev = 0.f;
  uint32_t xv = *(const uint32_t*)(xp_b + (u << 2) + (gp << 1));
  float tsv = ts_b[0];

  for (int s = 0; s < SEQ; s++){
    const int buf = s & 1;

    // delayed out store: previous step's h (drain hides under this step's compute)
    if (s > 0 && !odd) out_b[(size_t)(s - 1) * HID + u] = hn_prev;

    // prefetch next step
    uint32_t xn = 0u; float tsn = 0.f;
    if (s + 1 < SEQ){
      xn  = *(const uint32_t*)(xp_b + (size_t)(s + 1) * 1024 + (u << 2) + (gp << 1));
      tsn = ts_b[s + 1];
    }

    // one coalesced read: lane j holds {h word j, c word j}
    uint2 st = hc[buf][lane];

    // matvecs: SGPR broadcast via readlane, zero redundancy on Wall
    int a0 = 0, a1 = 0, ad = 0;
    #pragma unroll
    for (int jw = 0; jw < 64; jw++){
      int hs = __builtin_amdgcn_readlane((int)st.x, jw);
      a0 = sdot4_(ww0[jw], hs, a0);
      a1 = sdot4_(ww1[jw], hs, a1);
      int cs = __builtin_amdgcn_readlane((int)st.y, jw);
      ad = sdot4_(wd[jw], cs, ad);
    }

    // pre-activations for my two gate rows
    float pA = (float)a0 * SW + b0 + f16u_to_f32(xv & 0xffff);
    float pB = (float)a1 * SW + b1 + f16u_to_f32(xv >> 16);
    float qA = __shfl_xor(pA, 1);
    float qB = __shfl_xor(pB, 1);
    float pf = odd ? qA : pA;
    float pi = odd ? qB : pB;
    float po = odd ? pA : qA;
    float pc = odd ? pB : qB;

    float wdot = (float)ad * SWD + bD;
    float cs1  = tanh_(wdot);
    float cadj = (c_reg - cs1) + cs1 * tsv;
    float fg = sigm_(pf), ig = sigm_(pi), og = sigm_(po), ct = sigm_(pc);
    float cn = fg * cadj + ig * ct;
    float hn = og * tanh_(cn);
    c_reg = cn;
    hn_prev = hn;

    // publish next-step state (one writer per unit)
    if (!odd){
      int hq = __float2int_rn(hn * 127.f);
      hq = max(-127, min(127, hq));
      float cc = fminf(fmaxf(cn, -7.9f), 7.9f);
      int cq = __float2int_rn(cc * 15.875f);
      int nb = buf ^ 1;
      int8_t* base = (int8_t*)hc;
      base[(size_t)(nb * 64 + (u >> 2)) * 8 + (u & 3)]     = (int8_t)hq;
      base[(size_t)(nb * 64 + (u >> 2)) * 8 + 4 + (u & 3)] = (int8_t)cq;
    }
    xv = xn; tsv = tsn;
    __syncthreads();
  }
  if (!odd) out_b[(size_t)(SEQ - 1) * HID + u] = hn_prev;
}

extern "C" void kernel_launch(void* const* d_in, const int* in_sizes, int n_in,
                              void* d_out, int out_size, void* d_ws, size_t ws_size,
                              hipStream_t stream){
  const int*   codes  = (const int*)  d_in[0];
  const float* mask   = (const float*)d_in[1];
  const float* times  = (const float*)d_in[2];
  const float* emb    = (const float*)d_in[3];
  const float* Wall_w = (const float*)d_in[4];
  const float* Wall_b = (const float*)d_in[5];
  const float* Uall_w = (const float*)d_in[6];
  const float* Uall_b = (const float*)d_in[7];
  const float* Wd_w   = (const float*)d_in[8];
  const float* Wd_b   = (const float*)d_in[9];
  float* out = (float*)d_out;

  char* ws = (char*)d_ws;
  const size_t offWpk  = 0;          // 64*1024*4 = 262144
  const size_t offWdp  = 262144;     // 32*1024*4 = 131072 -> 393216
  const size_t offTs   = 393216;     // 131072 -> 524288
  const size_t offUh   = 524288;     // 524288 -> 1048576
  const size_t offXp2  = 1048576;    // 67108864 -> 68157440
  const size_t offXh   = 68157440;   // 16777216 -> 84934656

  uint32_t* wpk    = (uint32_t*)(ws + offWpk);
  uint32_t* wdp    = (uint32_t*)(ws + offWdp);
  float*    ts_all = (float*)   (ws + offTs);
  uint16_t* uh     = (uint16_t*)(ws + offUh);
  uint16_t* xp2    = (uint16_t*)(ws + offXp2);
  uint16_t* xh     = (uint16_t*)(ws + offXh);

  hipLaunchKernelGGL(pack_wall_r7, dim3(256), dim3(256), 0, stream, Wall_w, wpk);
  hipLaunchKernelGGL(pack_wd_r7,   dim3(128), dim3(256), 0, stream, Wd_w,   wdp);
  hipLaunchKernelGGL(pack_u16,     dim3(1024), dim3(256), 0, stream, Uall_w, uh, 1024 * 256);
  hipLaunchKernelGGL(ts_k,         dim3(128), dim3(256), 0, stream, times, ts_all);
  hipLaunchKernelGGL(gather_x,     dim3(BATCH * SEQ), dim3(256), 0, stream, codes, mask, emb, xh);
  hipLaunchKernelGGL(xp_gemm_mfma, dim3(8, 256), dim3(256), 0, stream, xh, uh, Uall_b, xp2);
  hipLaunchKernelGGL(recurrence,   dim3(BATCH), dim3(512), 0, stream,
                     wpk, wdp, Wall_b, Wd_b, xp2, ts_all, out);
}

// Round 8
// 556.855 us; speedup vs baseline: 1.1125x; 1.1125x over previous
//
#include <hip/hip_runtime.h>
#include <stdint.h>

#define BATCH 128
#define SEQ   256
#define NC    16
#define HID   256
#define G4    1024

typedef _Float16 half8 __attribute__((ext_vector_type(8)));
typedef float    f32x4 __attribute__((ext_vector_type(4)));
typedef int      i32x4 __attribute__((ext_vector_type(4)));

__device__ __forceinline__ uint16_t f32_to_f16u(float f){
  union { _Float16 h; uint16_t u; } c; c.h = (_Float16)f; return c.u;
}
__device__ __forceinline__ float f16u_to_f32(uint32_t u){
  union { uint16_t u; _Float16 h; } c; c.u = (uint16_t)u; return (float)c.h;
}
__device__ __forceinline__ float tanh_(float x){
  x = fminf(fmaxf(x, -15.f), 15.f);
  float e = __expf(2.f * x);
  return (e - 1.f) / (e + 1.f);
}
__device__ __forceinline__ float sigm_(float x){ return 1.f / (1.f + __expf(-x)); }

__device__ __forceinline__ uint32_t q4(const float* s, float sc){
  uint32_t r = 0;
  #pragma unroll
  for (int i = 0; i < 4; i++){
    int q = __float2int_rn(s[i] * sc);
    q = max(-127, min(127, q));
    r |= ((uint32_t)(q & 0xFF)) << (8 * i);
  }
  return r;
}

// ---- Wall pack as MFMA B-fragments ----
// recurrence reads ww[t][q] = wpkB[(t*4+q)*1024 + tid]; tid = w*64+l, c=l&15, r=l>>4
// B[k = q*64 + r*16 + j][col=c] = Wall[t*256 + w*16 + c][q*64 + r*16 + j]
__global__ void pack_wallB(const float* __restrict__ W, uint4* __restrict__ out){
  int L = blockIdx.x * blockDim.x + threadIdx.x;
  if (L >= 16 * 1024) return;
  int slot = L >> 10, tid = L & 1023;
  int t = slot >> 2, q = slot & 3;
  int w = tid >> 6, l = tid & 63;
  int c = l & 15, r = l >> 4;
  int row = t * 256 + w * 16 + c;
  int kb = q * 64 + r * 16;
  const float* src = W + (size_t)row * 256 + kb;
  uint4 v;
  v.x = q4(src +  0, 2032.f);
  v.y = q4(src +  4, 2032.f);
  v.z = q4(src +  8, 2032.f);
  v.w = q4(src + 12, 2032.f);
  out[L] = v;
}
// ---- Wd pack as MFMA B-fragments: wdB[q*1024 + tid]; row = w*16+c
__global__ void pack_wdB(const float* __restrict__ W, uint4* __restrict__ out){
  int L = blockIdx.x * blockDim.x + threadIdx.x;
  if (L >= 4 * 1024) return;
  int q = L >> 10, tid = L & 1023;
  int w = tid >> 6, l = tid & 63;
  int c = l & 15, r = l >> 4;
  int row = w * 16 + c;
  int kb = q * 64 + r * 16;
  const float* src = W + (size_t)row * 256 + kb;
  uint4 v;
  v.x = q4(src +  0, 2032.f);
  v.y = q4(src +  4, 2032.f);
  v.z = q4(src +  8, 2032.f);
  v.w = q4(src + 12, 2032.f);
  out[L] = v;
}

__global__ void pack_u16(const float* __restrict__ W, uint16_t* __restrict__ out, int n){
  int i = blockIdx.x * blockDim.x + threadIdx.x;
  if (i < n) out[i] = f32_to_f16u(W[i]);
}

__global__ void ts_k(const float* __restrict__ times, float* __restrict__ ts_all){
  int i = blockIdx.x * blockDim.x + threadIdx.x;
  if (i < BATCH * SEQ) ts_all[i] = 1.f / logf(times[i] + 2.7183f);
}

__global__ void gather_x(const int* __restrict__ codes, const float* __restrict__ mask,
                         const float* __restrict__ emb, uint16_t* __restrict__ xh){
  int bs = blockIdx.x;
  int t  = threadIdx.x;
  __shared__ int   scd[NC];
  __shared__ float smk[NC];
  if (t < NC){ scd[t] = codes[bs * NC + t]; smk[t] = mask[bs * NC + t]; }
  __syncthreads();
  float acc = 0.f;
  #pragma unroll
  for (int k = 0; k < NC; k++)
    acc += emb[(size_t)scd[k] * HID + t] * smk[k];
  xh[(size_t)bs * HID + t] = f32_to_f16u(acc);
}

// ---- xp GEMM via MFMA f16: C[m][n] = xh[m][k] * uh[n][k]; M=32768,N=1024,K=256
// output permuted: xp2[m][u*4+gate] f16, gate=n>>8, u=n&255
__global__ __launch_bounds__(256, 2) void xp_gemm_mfma(
    const uint16_t* __restrict__ xh, const uint16_t* __restrict__ uh,
    const float* __restrict__ Ub, uint16_t* __restrict__ xp2)
{
  __shared__ _Float16 As[128][40];
  __shared__ _Float16 Bs[128][40];
  const int tid = threadIdx.x;
  const int m0 = blockIdx.y * 128, n0 = blockIdx.x * 128;
  const int w = tid >> 6, l = tid & 63;
  const int wr = w >> 1, wc = w & 1;
  const int sr0 = tid >> 2, sk0 = (tid & 3) * 8;

  f32x4 acc[4][4];
  #pragma unroll
  for (int i = 0; i < 4; i++)
    #pragma unroll
    for (int j = 0; j < 4; j++)
      acc[i][j] = (f32x4){0.f, 0.f, 0.f, 0.f};

  for (int k0 = 0; k0 < 256; k0 += 32){
    uint4 a0 = *(const uint4*)(xh + (size_t)(m0 + sr0) * 256 + k0 + sk0);
    uint4 a1 = *(const uint4*)(xh + (size_t)(m0 + 64 + sr0) * 256 + k0 + sk0);
    uint4 b0 = *(const uint4*)(uh + (size_t)(n0 + sr0) * 256 + k0 + sk0);
    uint4 b1 = *(const uint4*)(uh + (size_t)(n0 + 64 + sr0) * 256 + k0 + sk0);
    __syncthreads();
    *(uint4*)&As[sr0][sk0]      = a0;
    *(uint4*)&As[64 + sr0][sk0] = a1;
    *(uint4*)&Bs[sr0][sk0]      = b0;
    *(uint4*)&Bs[64 + sr0][sk0] = b1;
    __syncthreads();
    half8 af[4], bf[4];
    #pragma unroll
    for (int i = 0; i < 4; i++)
      af[i] = *(half8*)&As[wr*64 + i*16 + (l & 15)][(l >> 4) * 8];
    #pragma unroll
    for (int j = 0; j < 4; j++)
      bf[j] = *(half8*)&Bs[wc*64 + j*16 + (l & 15)][(l >> 4) * 8];
    #pragma unroll
    for (int i = 0; i < 4; i++)
      #pragma unroll
      for (int j = 0; j < 4; j++)
        acc[i][j] = __builtin_amdgcn_mfma_f32_16x16x32_f16(af[i], bf[j], acc[i][j], 0, 0, 0);
  }

  const int gate = n0 >> 8;
  #pragma unroll
  for (int j = 0; j < 4; j++){
    int ncol = wc*64 + j*16 + (l & 15);
    float bs = Ub[n0 + ncol];
    int u = (n0 & 255) + ncol;
    #pragma unroll
    for (int i = 0; i < 4; i++){
      #pragma unroll
      for (int r = 0; r < 4; r++){
        int m_e = m0 + wr*64 + i*16 + (l >> 4)*4 + r;
        xp2[(size_t)m_e * 1024 + u*4 + gate] = f32_to_f16u(acc[i][j][r] + bs);
      }
    }
  }
}

// ---- recurrence: 128 blocks x 1024 threads (16 waves = 4/SIMD)
// Identical math to R6 (MFMA i8 replicated-A matvec). Change: raw lgkm-only barrier
// (global store/prefetch float across steps) + prefetch pinned to step top.
__global__ __launch_bounds__(1024, 4) void recurrence(
    const i32x4* __restrict__ wpkB,   // [16][1024]
    const i32x4* __restrict__ wdB,    // [4][1024]
    const float* __restrict__ Wall_b, const float* __restrict__ Wd_b,
    const uint16_t* __restrict__ xp2, const float* __restrict__ ts_all,
    float* __restrict__ out)
{
  const int b = blockIdx.x, tid = threadIdx.x;
  const int l = tid & 63;
  const int c = l & 15, r = l >> 4;
  const int U = (tid >> 6) * 16 + c;     // unit this lane owns

  __shared__ __align__(16) uint32_t h8[2][64];  // h[256] i8, scale 127
  __shared__ __align__(16) uint32_t c8[2][64];  // c[256] i8, scale 15.875

  i32x4 ww[4][4];
  #pragma unroll
  for (int t = 0; t < 4; t++)
    #pragma unroll
    for (int q = 0; q < 4; q++)
      ww[t][q] = wpkB[(t * 4 + q) * 1024 + tid];
  i32x4 wd[4];
  #pragma unroll
  for (int q = 0; q < 4; q++) wd[q] = wdB[q * 1024 + tid];

  const float bWf = Wall_b[U];
  const float bWi = Wall_b[U + 256];
  const float bWo = Wall_b[U + 512];
  const float bWc = Wall_b[U + 768];
  const float bD  = Wd_b[U];
  const float SW  = 1.f / (2032.f * 127.f);
  const float SWD = 1.f / (2032.f * 15.875f);

  if (tid < 128) ((uint32_t*)h8)[tid] = 0u;
  else if (tid < 256) ((uint32_t*)c8)[tid - 128] = 0u;
  __syncthreads();

  const uint16_t* xp_b = xp2 + (size_t)b * SEQ * 1024;
  const float*    ts_b = ts_all + (size_t)b * SEQ;
  float* out_b = out + (size_t)b * SEQ * HID;

  float c_reg = 0.f;
  float hn_prev = 0.f;
  uint2 xv = *(const uint2*)(xp_b + (U << 2));
  float tsv = ts_b[0];

  for (int s = 0; s < SEQ; s++){
    const int buf = s & 1;

    // (A) early prefetch of next-step inputs — issued at step top, consumed next
    // iteration, so the auto vmcnt wait lands ~a full step later (fully hidden)
    uint2 xn = make_uint2(0u, 0u); float tsn = 0.f;
    if (s + 1 < SEQ){
      xn  = *(const uint2*)(xp_b + (size_t)(s + 1) * 1024 + (U << 2));
      tsn = ts_b[s + 1];
    }
    // (B) delayed store of previous step's h — nothing ever waits on it
    if (s > 0 && r == 0) out_b[(size_t)(s - 1) * HID + U] = hn_prev;
    __builtin_amdgcn_sched_barrier(0);   // pin (A)/(B) issue before the compute below

    // A-fragments: h and c replicated (addr uniform per 16-lane group, conflict-free)
    const char* hbase = (const char*)&h8[buf][0];
    const char* cbase = (const char*)&c8[buf][0];
    i32x4 hA[4], cA[4];
    #pragma unroll
    for (int q = 0; q < 4; q++){
      hA[q] = *(const i32x4*)(hbase + q * 64 + r * 16);
      cA[q] = *(const i32x4*)(cbase + q * 64 + r * 16);
    }

    // Wd matvec on MFMA pipe
    i32x4 ad = (i32x4){0, 0, 0, 0};
    #pragma unroll
    for (int q = 0; q < 4; q++)
      ad = __builtin_amdgcn_mfma_i32_16x16x64_i8(cA[q], wd[q], ad, 0, 0, 0);

    // Wall matvec: 4 gate tiles
    i32x4 a0 = (i32x4){0,0,0,0}, a1 = (i32x4){0,0,0,0}, a2 = (i32x4){0,0,0,0}, a3 = (i32x4){0,0,0,0};
    #pragma unroll
    for (int q = 0; q < 4; q++) a0 = __builtin_amdgcn_mfma_i32_16x16x64_i8(hA[q], ww[0][q], a0, 0, 0, 0);
    #pragma unroll
    for (int q = 0; q < 4; q++) a1 = __builtin_amdgcn_mfma_i32_16x16x64_i8(hA[q], ww[1][q], a1, 0, 0, 0);
    #pragma unroll
    for (int q = 0; q < 4; q++) a2 = __builtin_amdgcn_mfma_i32_16x16x64_i8(hA[q], ww[2][q], a2, 0, 0, 0);
    #pragma unroll
    for (int q = 0; q < 4; q++) a3 = __builtin_amdgcn_mfma_i32_16x16x64_i8(hA[q], ww[3][q], a3, 0, 0, 0);

    // gate math (all lanes; replicas redundant but uniform)
    float pf = (float)a0[0] * SW + bWf + f16u_to_f32(xv.x & 0xffff);
    float pi = (float)a1[0] * SW + bWi + f16u_to_f32(xv.x >> 16);
    float po = (float)a2[0] * SW + bWo + f16u_to_f32(xv.y & 0xffff);
    float pc = (float)a3[0] * SW + bWc + f16u_to_f32(xv.y >> 16);
    float wdot = (float)ad[0] * SWD + bD;

    float fg = sigm_(pf), ig = sigm_(pi), og = sigm_(po), ct = sigm_(pc);
    float cs1  = tanh_(wdot);
    float cadj = (c_reg - cs1) + cs1 * tsv;
    float cn = fg * cadj + ig * ct;
    float hn = og * tanh_(cn);
    c_reg = cn;
    hn_prev = hn;

    // quantize + publish next-step state (replica 0 only)
    if (r == 0){
      int hq = __float2int_rn(hn * 127.f);
      hq = max(-127, min(127, hq));
      float cc = fminf(fmaxf(cn, -7.9f), 7.9f);
      int cq = __float2int_rn(cc * 15.875f);
      ((int8_t*)&h8[buf ^ 1][0])[U] = (int8_t)hq;
      ((int8_t*)&c8[buf ^ 1][0])[U] = (int8_t)cq;
    }
    xv = xn; tsv = tsn;

    // raw barrier: wait LDS only (state publish); global loads/stores float across.
    asm volatile("s_waitcnt lgkmcnt(0)\n\ts_barrier" ::: "memory");
    __builtin_amdgcn_sched_barrier(0);   // rule #18: fence scheduler at the asm wait
  }
  if (r == 0) out_b[(size_t)(SEQ - 1) * HID + U] = hn_prev;
}

extern "C" void kernel_launch(void* const* d_in, const int* in_sizes, int n_in,
                              void* d_out, int out_size, void* d_ws, size_t ws_size,
                              hipStream_t stream){
  const int*   codes  = (const int*)  d_in[0];
  const float* mask   = (const float*)d_in[1];
  const float* times  = (const float*)d_in[2];
  const float* emb    = (const float*)d_in[3];
  const float* Wall_w = (const float*)d_in[4];
  const float* Wall_b = (const float*)d_in[5];
  const float* Uall_w = (const float*)d_in[6];
  const float* Uall_b = (const float*)d_in[7];
  const float* Wd_w   = (const float*)d_in[8];
  const float* Wd_b   = (const float*)d_in[9];
  float* out = (float*)d_out;

  char* ws = (char*)d_ws;
  const size_t offWpk  = 0;          // 262144
  const size_t offWd   = 262144;     // 65536   -> 327680
  const size_t offTs   = 327680;     // 131072  -> 458752
  const size_t offUh   = 458752;     // 524288  -> 983040
  const size_t offXp2  = 983040;     // 67108864-> 68091904
  const size_t offXh   = 68091904;   // 16777216-> 84869120

  uint4*    wpkB   = (uint4*)   (ws + offWpk);
  uint4*    wdB    = (uint4*)   (ws + offWd);
  float*    ts_all = (float*)   (ws + offTs);
  uint16_t* uh     = (uint16_t*)(ws + offUh);
  uint16_t* xp2    = (uint16_t*)(ws + offXp2);
  uint16_t* xh     = (uint16_t*)(ws + offXh);

  hipLaunchKernelGGL(pack_wallB, dim3(64), dim3(256), 0, stream, Wall_w, wpkB);
  hipLaunchKernelGGL(pack_wdB,   dim3(16), dim3(256), 0, stream, Wd_w,   wdB);
  hipLaunchKernelGGL(pack_u16,   dim3(1024), dim3(256), 0, stream, Uall_w, uh, 1024 * 256);
  hipLaunchKernelGGL(ts_k,       dim3(128), dim3(256), 0, stream, times, ts_all);
  hipLaunchKernelGGL(gather_x,   dim3(BATCH * SEQ), dim3(256), 0, stream, codes, mask, emb, xh);
  hipLaunchKernelGGL(xp_gemm_mfma, dim3(8, 256), dim3(256), 0, stream, xh, uh, Uall_b, xp2);
  hipLaunchKernelGGL(recurrence, dim3(BATCH), dim3(1024), 0, stream,
                     (const i32x4*)wpkB, (const i32x4*)wdB, Wall_b, Wd_b, xp2, ts_all, out);
}

// Round 9
// 510.948 us; speedup vs baseline: 1.2125x; 1.0898x over previous
//
#include <hip/hip_runtime.h>
#include <stdint.h>

#define BATCH 128
#define SEQ   256
#define NC    16
#define HID   256
#define G4    1024

typedef _Float16 half8 __attribute__((ext_vector_type(8)));
typedef float    f32x4 __attribute__((ext_vector_type(4)));
typedef int      i32x4 __attribute__((ext_vector_type(4)));

__device__ __forceinline__ uint16_t f32_to_f16u(float f){
  union { _Float16 h; uint16_t u; } c; c.h = (_Float16)f; return c.u;
}
__device__ __forceinline__ float f16u_to_f32(uint32_t u){
  union { uint16_t u; _Float16 h; } c; c.u = (uint16_t)u; return (float)c.h;
}
__device__ __forceinline__ float tanh_(float x){
  x = fminf(fmaxf(x, -15.f), 15.f);
  float e = __expf(2.f * x);
  return (e - 1.f) / (e + 1.f);
}
__device__ __forceinline__ float sigm_(float x){ return 1.f / (1.f + __expf(-x)); }

__device__ __forceinline__ uint32_t q4(const float* s, float sc){
  uint32_t r = 0;
  #pragma unroll
  for (int i = 0; i < 4; i++){
    int q = __float2int_rn(s[i] * sc);
    q = max(-127, min(127, q));
    r |= ((uint32_t)(q & 0xFF)) << (8 * i);
  }
  return r;
}

// ---- Wall pack as MFMA B-fragments, 2 tiles per wave ----
// recurrence reads ww[tau][t][q] = wpkB[((tau*4+t)*4+q)*512 + tid]
// tid = w*64+l (w<8), c=l&15, r=l>>4
// B[k = q*64 + r*16 + j][col=c] = Wall[t*256 + w*32 + tau*16 + c][q*64 + r*16 + j]
__global__ void pack_wallB2(const float* __restrict__ W, uint4* __restrict__ out){
  int L = blockIdx.x * blockDim.x + threadIdx.x;
  if (L >= 32 * 512) return;
  int slot = L >> 9, tid = L & 511;
  int tau = slot >> 4, t = (slot >> 2) & 3, q = slot & 3;
  int w = tid >> 6, l = tid & 63;
  int c = l & 15, r = l >> 4;
  int row = t * 256 + w * 32 + tau * 16 + c;
  int kb = q * 64 + r * 16;
  const float* src = W + (size_t)row * 256 + kb;
  uint4 v;
  v.x = q4(src +  0, 2032.f);
  v.y = q4(src +  4, 2032.f);
  v.z = q4(src +  8, 2032.f);
  v.w = q4(src + 12, 2032.f);
  out[L] = v;
}
// ---- Wd pack: wd[tau][q] = wdB[(tau*4+q)*512 + tid]; row = w*32 + tau*16 + c
__global__ void pack_wdB2(const float* __restrict__ W, uint4* __restrict__ out){
  int L = blockIdx.x * blockDim.x + threadIdx.x;
  if (L >= 8 * 512) return;
  int slot = L >> 9, tid = L & 511;
  int tau = slot >> 2, q = slot & 3;
  int w = tid >> 6, l = tid & 63;
  int c = l & 15, r = l >> 4;
  int row = w * 32 + tau * 16 + c;
  int kb = q * 64 + r * 16;
  const float* src = W + (size_t)row * 256 + kb;
  uint4 v;
  v.x = q4(src +  0, 2032.f);
  v.y = q4(src +  4, 2032.f);
  v.z = q4(src +  8, 2032.f);
  v.w = q4(src + 12, 2032.f);
  out[L] = v;
}

__global__ void pack_u16(const float* __restrict__ W, uint16_t* __restrict__ out, int n){
  int i = blockIdx.x * blockDim.x + threadIdx.x;
  if (i < n) out[i] = f32_to_f16u(W[i]);
}

__global__ void ts_k(const float* __restrict__ times, float* __restrict__ ts_all){
  int i = blockIdx.x * blockDim.x + threadIdx.x;
  if (i < BATCH * SEQ) ts_all[i] = 1.f / logf(times[i] + 2.7183f);
}

__global__ void gather_x(const int* __restrict__ codes, const float* __restrict__ mask,
                         const float* __restrict__ emb, uint16_t* __restrict__ xh){
  int bs = blockIdx.x;
  int t  = threadIdx.x;
  __shared__ int   scd[NC];
  __shared__ float smk[NC];
  if (t < NC){ scd[t] = codes[bs * NC + t]; smk[t] = mask[bs * NC + t]; }
  __syncthreads();
  float acc = 0.f;
  #pragma unroll
  for (int k = 0; k < NC; k++)
    acc += emb[(size_t)scd[k] * HID + t] * smk[k];
  xh[(size_t)bs * HID + t] = f32_to_f16u(acc);
}

// ---- xp GEMM via MFMA f16 (unchanged): xp2[m][u*4+gate] f16
__global__ __launch_bounds__(256, 2) void xp_gemm_mfma(
    const uint16_t* __restrict__ xh, const uint16_t* __restrict__ uh,
    const float* __restrict__ Ub, uint16_t* __restrict__ xp2)
{
  __shared__ _Float16 As[128][40];
  __shared__ _Float16 Bs[128][40];
  const int tid = threadIdx.x;
  const int m0 = blockIdx.y * 128, n0 = blockIdx.x * 128;
  const int w = tid >> 6, l = tid & 63;
  const int wr = w >> 1, wc = w & 1;
  const int sr0 = tid >> 2, sk0 = (tid & 3) * 8;

  f32x4 acc[4][4];
  #pragma unroll
  for (int i = 0; i < 4; i++)
    #pragma unroll
    for (int j = 0; j < 4; j++)
      acc[i][j] = (f32x4){0.f, 0.f, 0.f, 0.f};

  for (int k0 = 0; k0 < 256; k0 += 32){
    uint4 a0 = *(const uint4*)(xh + (size_t)(m0 + sr0) * 256 + k0 + sk0);
    uint4 a1 = *(const uint4*)(xh + (size_t)(m0 + 64 + sr0) * 256 + k0 + sk0);
    uint4 b0 = *(const uint4*)(uh + (size_t)(n0 + sr0) * 256 + k0 + sk0);
    uint4 b1 = *(const uint4*)(uh + (size_t)(n0 + 64 + sr0) * 256 + k0 + sk0);
    __syncthreads();
    *(uint4*)&As[sr0][sk0]      = a0;
    *(uint4*)&As[64 + sr0][sk0] = a1;
    *(uint4*)&Bs[sr0][sk0]      = b0;
    *(uint4*)&Bs[64 + sr0][sk0] = b1;
    __syncthreads();
    half8 af[4], bf[4];
    #pragma unroll
    for (int i = 0; i < 4; i++)
      af[i] = *(half8*)&As[wr*64 + i*16 + (l & 15)][(l >> 4) * 8];
    #pragma unroll
    for (int j = 0; j < 4; j++)
      bf[j] = *(half8*)&Bs[wc*64 + j*16 + (l & 15)][(l >> 4) * 8];
    #pragma unroll
    for (int i = 0; i < 4; i++)
      #pragma unroll
      for (int j = 0; j < 4; j++)
        acc[i][j] = __builtin_amdgcn_mfma_f32_16x16x32_f16(af[i], bf[j], acc[i][j], 0, 0, 0);
  }

  const int gate = n0 >> 8;
  #pragma unroll
  for (int j = 0; j < 4; j++){
    int ncol = wc*64 + j*16 + (l & 15);
    float bs = Ub[n0 + ncol];
    int u = (n0 & 255) + ncol;
    #pragma unroll
    for (int i = 0; i < 4; i++){
      #pragma unroll
      for (int r = 0; r < 4; r++){
        int m_e = m0 + wr*64 + i*16 + (l >> 4)*4 + r;
        xp2[(size_t)m_e * 1024 + u*4 + gate] = f32_to_f16u(acc[i][j][r] + bs);
      }
    }
  }
}

// ---- recurrence: 128 blocks x 512 threads (8 waves, 2/SIMD)
// Wave w owns 32 units via two 16-col MFMA tile sets (tau=0,1); A-fragments
// (h,c replicas) are read ONCE per wave and shared by both tiles -> DS halves.
__global__ __launch_bounds__(512) void recurrence(
    const i32x4* __restrict__ wpkB,   // [32][512]
    const i32x4* __restrict__ wdB,    // [8][512]
    const float* __restrict__ Wall_b, const float* __restrict__ Wd_b,
    const uint16_t* __restrict__ xp2, const float* __restrict__ ts_all,
    float* __restrict__ out)
{
  const int b = blockIdx.x, tid = threadIdx.x;
  const int l = tid & 63;
  const int c = l & 15, r = l >> 4;
  const int w = tid >> 6;
  const int U0 = w * 32 + c;          // tau=0 unit
  const int U1 = U0 + 16;             // tau=1 unit

  __shared__ __align__(16) uint32_t h8[2][64];  // h[256] i8, scale 127
  __shared__ __align__(16) uint32_t c8[2][64];  // c[256] i8, scale 15.875

  i32x4 ww[2][4][4];
  #pragma unroll
  for (int tau = 0; tau < 2; tau++)
    #pragma unroll
    for (int t = 0; t < 4; t++)
      #pragma unroll
      for (int q = 0; q < 4; q++)
        ww[tau][t][q] = wpkB[(((tau * 4 + t) * 4) + q) * 512 + tid];
  i32x4 wd[2][4];
  #pragma unroll
  for (int tau = 0; tau < 2; tau++)
    #pragma unroll
    for (int q = 0; q < 4; q++)
      wd[tau][q] = wdB[(tau * 4 + q) * 512 + tid];

  float bW[2][4], bD[2];
  #pragma unroll
  for (int tau = 0; tau < 2; tau++){
    int U = tau ? U1 : U0;
    bW[tau][0] = Wall_b[U];
    bW[tau][1] = Wall_b[U + 256];
    bW[tau][2] = Wall_b[U + 512];
    bW[tau][3] = Wall_b[U + 768];
    bD[tau]    = Wd_b[U];
  }
  const float SW  = 1.f / (2032.f * 127.f);
  const float SWD = 1.f / (2032.f * 15.875f);

  if (tid < 128) ((uint32_t*)h8)[tid] = 0u;
  else if (tid < 256) ((uint32_t*)c8)[tid - 128] = 0u;
  __syncthreads();

  const uint16_t* xp_b = xp2 + (size_t)b * SEQ * 1024;
  const float*    ts_b = ts_all + (size_t)b * SEQ;
  float* out_b = out + (size_t)b * SEQ * HID;

  float c_reg[2] = {0.f, 0.f};
  float hn_prev[2] = {0.f, 0.f};
  uint2 xv[2];
  xv[0] = *(const uint2*)(xp_b + (U0 << 2));
  xv[1] = *(const uint2*)(xp_b + (U1 << 2));
  float tsv = ts_b[0];

  for (int s = 0; s < SEQ; s++){
    const int buf = s & 1;

    // delayed store of previous step's h
    if (s > 0 && r == 0){
      out_b[(size_t)(s - 1) * HID + U0] = hn_prev[0];
      out_b[(size_t)(s - 1) * HID + U1] = hn_prev[1];
    }
    // prefetch next step
    uint2 xn0 = make_uint2(0u, 0u), xn1 = make_uint2(0u, 0u);
    float tsn = 0.f;
    if (s + 1 < SEQ){
      xn0 = *(const uint2*)(xp_b + (size_t)(s + 1) * 1024 + (U0 << 2));
      xn1 = *(const uint2*)(xp_b + (size_t)(s + 1) * 1024 + (U1 << 2));
      tsn = ts_b[s + 1];
    }

    // A-fragments: h and c replicated (uniform per 16-lane group), SHARED by both tiles
    const char* hbase = (const char*)&h8[buf][0];
    const char* cbase = (const char*)&c8[buf][0];
    i32x4 hA[4], cA[4];
    #pragma unroll
    for (int q = 0; q < 4; q++){
      hA[q] = *(const i32x4*)(hbase + q * 64 + r * 16);
      cA[q] = *(const i32x4*)(cbase + q * 64 + r * 16);
    }

    #pragma unroll
    for (int tau = 0; tau < 2; tau++){
      // Wd matvec
      i32x4 ad = (i32x4){0, 0, 0, 0};
      #pragma unroll
      for (int q = 0; q < 4; q++)
        ad = __builtin_amdgcn_mfma_i32_16x16x64_i8(cA[q], wd[tau][q], ad, 0, 0, 0);
      // Wall matvec: 4 gate tiles
      i32x4 a0 = (i32x4){0,0,0,0}, a1 = (i32x4){0,0,0,0}, a2 = (i32x4){0,0,0,0}, a3 = (i32x4){0,0,0,0};
      #pragma unroll
      for (int q = 0; q < 4; q++) a0 = __builtin_amdgcn_mfma_i32_16x16x64_i8(hA[q], ww[tau][0][q], a0, 0, 0, 0);
      #pragma unroll
      for (int q = 0; q < 4; q++) a1 = __builtin_amdgcn_mfma_i32_16x16x64_i8(hA[q], ww[tau][1][q], a1, 0, 0, 0);
      #pragma unroll
      for (int q = 0; q < 4; q++) a2 = __builtin_amdgcn_mfma_i32_16x16x64_i8(hA[q], ww[tau][2][q], a2, 0, 0, 0);
      #pragma unroll
      for (int q = 0; q < 4; q++) a3 = __builtin_amdgcn_mfma_i32_16x16x64_i8(hA[q], ww[tau][3][q], a3, 0, 0, 0);

      uint2 xt = tau ? xv[1] : xv[0];
      float pf = (float)a0[0] * SW + bW[tau][0] + f16u_to_f32(xt.x & 0xffff);
      float pi = (float)a1[0] * SW + bW[tau][1] + f16u_to_f32(xt.x >> 16);
      float po = (float)a2[0] * SW + bW[tau][2] + f16u_to_f32(xt.y & 0xffff);
      float pc = (float)a3[0] * SW + bW[tau][3] + f16u_to_f32(xt.y >> 16);
      float wdot = (float)ad[0] * SWD + bD[tau];

      float fg = sigm_(pf), ig = sigm_(pi), og = sigm_(po), ct = sigm_(pc);
      float cs1  = tanh_(wdot);
      float cadj = (c_reg[tau] - cs1) + cs1 * tsv;
      float cn = fg * cadj + ig * ct;
      float hn = og * tanh_(cn);
      c_reg[tau] = cn;
      hn_prev[tau] = hn;

      if (r == 0){
        int hq = __float2int_rn(hn * 127.f);
        hq = max(-127, min(127, hq));
        float cc = fminf(fmaxf(cn, -7.9f), 7.9f);
        int cq = __float2int_rn(cc * 15.875f);
        int U = tau ? U1 : U0;
        ((int8_t*)&h8[buf ^ 1][0])[U] = (int8_t)hq;
        ((int8_t*)&c8[buf ^ 1][0])[U] = (int8_t)cq;
      }
    }
    xv[0] = xn0; xv[1] = xn1; tsv = tsn;
    __syncthreads();
  }
  if (r == 0){
    out_b[(size_t)(SEQ - 1) * HID + U0] = hn_prev[0];
    out_b[(size_t)(SEQ - 1) * HID + U1] = hn_prev[1];
  }
}

extern "C" void kernel_launch(void* const* d_in, const int* in_sizes, int n_in,
                              void* d_out, int out_size, void* d_ws, size_t ws_size,
                              hipStream_t stream){
  const int*   codes  = (const int*)  d_in[0];
  const float* mask   = (const float*)d_in[1];
  const float* times  = (const float*)d_in[2];
  const float* emb    = (const float*)d_in[3];
  const float* Wall_w = (const float*)d_in[4];
  const float* Wall_b = (const float*)d_in[5];
  const float* Uall_w = (const float*)d_in[6];
  const float* Uall_b = (const float*)d_in[7];
  const float* Wd_w   = (const float*)d_in[8];
  const float* Wd_b   = (const float*)d_in[9];
  float* out = (float*)d_out;

  char* ws = (char*)d_ws;
  const size_t offWpk  = 0;          // 32*512*16 = 262144
  const size_t offWd   = 262144;     // 8*512*16 = 65536 -> 327680
  const size_t offTs   = 327680;     // 131072  -> 458752
  const size_t offUh   = 458752;     // 524288  -> 983040
  const size_t offXp2  = 983040;     // 67108864-> 68091904
  const size_t offXh   = 68091904;   // 16777216-> 84869120

  uint4*    wpkB   = (uint4*)   (ws + offWpk);
  uint4*    wdB    = (uint4*)   (ws + offWd);
  float*    ts_all = (float*)   (ws + offTs);
  uint16_t* uh     = (uint16_t*)(ws + offUh);
  uint16_t* xp2    = (uint16_t*)(ws + offXp2);
  uint16_t* xh     = (uint16_t*)(ws + offXh);

  hipLaunchKernelGGL(pack_wallB2, dim3(64), dim3(256), 0, stream, Wall_w, wpkB);
  hipLaunchKernelGGL(pack_wdB2,   dim3(16), dim3(256), 0, stream, Wd_w,   wdB);
  hipLaunchKernelGGL(pack_u16,    dim3(1024), dim3(256), 0, stream, Uall_w, uh, 1024 * 256);
  hipLaunchKernelGGL(ts_k,        dim3(128), dim3(256), 0, stream, times, ts_all);
  hipLaunchKernelGGL(gather_x,    dim3(BATCH * SEQ), dim3(256), 0, stream, codes, mask, emb, xh);
  hipLaunchKernelGGL(xp_gemm_mfma, dim3(8, 256), dim3(256), 0, stream, xh, uh, Uall_b, xp2);
  hipLaunchKernelGGL(recurrence,  dim3(BATCH), dim3(512), 0, stream,
                     (const i32x4*)wpkB, (const i32x4*)wdB, Wall_b, Wd_b, xp2, ts_all, out);
}